// Round 3
// baseline (1315.671 us; speedup 1.0000x reference)
//
#include <hip/hip_runtime.h>
#include <hip/hip_bf16.h>

typedef __attribute__((ext_vector_type(8))) short short8;
typedef __attribute__((ext_vector_type(4))) float f32x4;

#define HW_GRID (256 * 512)
#define WS_WEIGHTS_USHORTS 393216        // 786 KB of bf16 weight fragments
#define WS_GRID_USHORTS (HW_GRID * 256)  // 67 MB bf16 HWC grid

__device__ __forceinline__ unsigned short f2bf(float f) {
  union { float f; unsigned int u; } v; v.f = f;
  unsigned int u = v.u;
  u += 0x7FFFu + ((u >> 16) & 1u);   // round-to-nearest-even
  return (unsigned short)(u >> 16);
}
__device__ __forceinline__ float bf2f(unsigned short b) {
  union { unsigned int u; float f; } v; v.u = ((unsigned int)b) << 16;
  return v.f;
}

// MFMA B-fragment layout for 16x16x32: B[k][j] lives at lane=((k%32)/8)*16 + j%16, elem=k%8
__device__ __forceinline__ int frag_off(int k, int j, int nf) {
  int kstep = k >> 5, ke = k & 31;
  int lane = ((ke >> 3) << 4) | (j & 15);
  int e = ke & 7;
  int nfrag = j >> 4;
  return (((kstep * nf + nfrag) << 6) + lane) * 8 + e;
}

__global__ void prep_weights(const float* __restrict__ w1, const float* __restrict__ w2,
                             const float* __restrict__ w3, unsigned short* __restrict__ ws) {
  int idx = blockIdx.x * 256 + threadIdx.x;
  if (idx < 65536) {               // w_pos1: K=256 (padded from 231) x N=256
    int k = idx >> 8, j = idx & 255;
    float v = (k < 231) ? w1[k * 256 + j] : 0.0f;
    ws[frag_off(k, j, 16)] = f2bf(v);
  }
  if (idx < 131072) {              // w_pos2: K=256 x N=512
    int k = idx >> 9, j = idx & 511;
    ws[65536 + frag_off(k, j, 32)] = f2bf(w2[k * 512 + j]);
  }
  if (idx < 196608) {              // w_pred1: K=768 x N=256
    int k = idx >> 8, j = idx & 255;
    ws[196608 + frag_off(k, j, 16)] = f2bf(w3[k * 256 + j]);
  }
}

// CHW fp32 -> HWC bf16 transpose. Block: 256 thr, 32 consecutive pixels x 256 ch.
__global__ __launch_bounds__(256) void prep_grid(const float* __restrict__ grid,
                                                 unsigned short* __restrict__ gh) {
  __shared__ unsigned short t_lds[32][264];   // +8 pad: spreads LDS banks on read
  const int pix0 = blockIdx.x * 32;
  const int xl = threadIdx.x & 31;            // pixel within block
  const int cg = threadIdx.x >> 5;            // 8 channel groups
#pragma unroll 8
  for (int cc = 0; cc < 32; ++cc) {
    int c = cg * 32 + cc;
    t_lds[xl][c] = f2bf(grid[(size_t)c * HW_GRID + pix0 + xl]);  // coalesced along x
  }
  __syncthreads();
  const int p = threadIdx.x >> 3;             // pixel
  const int s = threadIdx.x & 7;              // 32-ch slice
  unsigned short* dst = gh + ((size_t)(pix0 + p)) * 256 + s * 32;
  const unsigned short* src = &t_lds[p][s * 32];
#pragma unroll
  for (int u = 0; u < 4; ++u)
    *reinterpret_cast<short8*>(dst + u * 8) =
        *reinterpret_cast<const short8*>(src + u * 8);           // coalesced along c
}

// XOR-swizzled LDS index (ushort units). Kills 32-way bank conflict on
// stride-512B row-major ds_read_b128 (Guideline 4 / T2).
__device__ __forceinline__ int swz(int row, int col) {
  int byte = (col << 1) ^ ((row & 7) << 4);
  return row * 256 + (byte >> 1);
}

// A-tile (64 x 256, bf16, swizzled LDS) @ B (frag-order) -> acc[4][NW], K=256
template<int NW>
__device__ __forceinline__ void gemm_mfma(const unsigned short* __restrict__ At,
                                          const short8* __restrict__ Bf,
                                          int nftot, int nf0, int lane,
                                          f32x4 acc[4][NW]) {
  const int arow = lane & 15;
  const int acol = (lane >> 4) << 3;
  for (int ks = 0; ks < 8; ++ks) {
    short8 a[4];
#pragma unroll
    for (int m = 0; m < 4; ++m)
      a[m] = *reinterpret_cast<const short8*>(&At[swz(m * 16 + arow, ks * 32 + acol)]);
#pragma unroll
    for (int n = 0; n < NW; ++n) {
      short8 b = Bf[(ks * nftot + nf0 + n) * 64 + lane];
#pragma unroll
      for (int m = 0; m < 4; ++m)
        acc[m][n] = __builtin_amdgcn_mfma_f32_16x16x32_bf16(a[m], b, acc[m][n], 0, 0, 0);
    }
  }
}

// C layout: col = lane&15, row = (lane>>4)*4 + reg  [measured m89/m91]
template<int NW, bool RELU>
__device__ __forceinline__ void epilogue(f32x4 acc[4][NW], const float* __restrict__ bias,
                                         int bcol0, unsigned short* __restrict__ dst,
                                         int dcol0, int lane) {
  const int jlo = lane & 15;
  const int rhi = (lane >> 4) << 2;
#pragma unroll
  for (int n = 0; n < NW; ++n) {
    float bv = bias[bcol0 + n * 16 + jlo];
#pragma unroll
    for (int m = 0; m < 4; ++m) {
#pragma unroll
      for (int t = 0; t < 4; ++t) {
        float v = acc[m][n][t] + bv;
        if (RELU) v = fmaxf(v, 0.0f);
        dst[swz(m * 16 + rhi + t, dcol0 + n * 16 + jlo)] = f2bf(v);
      }
    }
  }
}

template<bool HWC>
__global__ __launch_bounds__(512, 4) void fused_decoder(
    const float* __restrict__ grid, const float* __restrict__ sgrad,
    const float* __restrict__ qpos, const float* __restrict__ quinf,
    const float* __restrict__ qsdf, const float* __restrict__ qnrm,
    const float* __restrict__ qflow,
    const float* __restrict__ b1, const float* __restrict__ b2,
    const float* __restrict__ b3, const float* __restrict__ w4,
    const float* __restrict__ b4,
    const unsigned short* __restrict__ wsh,
    float* __restrict__ out, int N) {
  // A: ff -> geo -> pos_enc half1 -> pos_enc half2.  B: h -> h2.
  __shared__ __align__(16) unsigned short A_lds[64 * 256];   // 32 KB
  __shared__ __align__(16) unsigned short B_lds[64 * 256];   // 32 KB
  __shared__ int qo_[4][64];
  __shared__ float qw[4][64];
  __shared__ float id_lds[64][12];

  const int tid = threadIdx.x;
  const int lane = tid & 63;
  const int wid = tid >> 6;
  const int row0 = blockIdx.x << 6;
  const short8* WF = (const short8*)wsh;            // w_pos1 frags
  const short8* WF2 = (const short8*)(wsh + 65536); // w_pos2
  const short8* WF3 = (const short8*)(wsh + 196608);// w_pred1 (24 ksteps x 16 nf)

  // ---- Phase 0a: per-row coords, sdf-grad gather, identity (threads 0..63)
  if (tid < 64) {
    const int r = tid;
    int g = row0 + r; if (g >= N) g = N - 1;
    float px = qpos[g * 2], py = qpos[g * 2 + 1];
    float xn = 2.0f * (px - (-2.0f)) / 6.0f - 1.0f;
    float yn = 2.0f * (py - (-1.5f)) / 3.0f - 1.0f;
    xn = fminf(fmaxf(xn, -1.0f), 1.0f);
    yn = fminf(fmaxf(yn, -1.0f), 1.0f);
    float ix = (xn + 1.0f) * 0.5f * 511.0f;
    float iy = (yn + 1.0f) * 0.5f * 255.0f;
    float x0f = floorf(ix), y0f = floorf(iy);
    float wx = ix - x0f, wy = iy - y0f;
    int x0 = (int)fminf(fmaxf(x0f, 0.0f), 511.0f);
    int x1 = (int)fminf(fmaxf(x0f + 1.0f, 0.0f), 511.0f);
    int y0 = (int)fminf(fmaxf(y0f, 0.0f), 255.0f);
    int y1 = (int)fminf(fmaxf(y0f + 1.0f, 0.0f), 255.0f);
    int o00 = y0 * 512 + x0, o01 = y0 * 512 + x1, o10 = y1 * 512 + x0, o11 = y1 * 512 + x1;
    qo_[0][r] = o00; qo_[1][r] = o01; qo_[2][r] = o10; qo_[3][r] = o11;
    float w00 = (1.0f - wx) * (1.0f - wy), w01 = wx * (1.0f - wy);
    float w10 = (1.0f - wx) * wy,          w11 = wx * wy;
    qw[0][r] = w00; qw[1][r] = w01; qw[2][r] = w10; qw[3][r] = w11;
    float sg0 = w00 * sgrad[o00] + w01 * sgrad[o01] + w10 * sgrad[o10] + w11 * sgrad[o11];
    const float* s1 = sgrad + HW_GRID;
    float sg1 = w00 * s1[o00] + w01 * s1[o01] + w10 * s1[o10] + w11 * s1[o11];
    float idv[11] = {px, py, quinf[g * 2], quinf[g * 2 + 1], qsdf[g], sg0, sg1,
                     qnrm[g * 2], qnrm[g * 2 + 1], qflow[g * 2], qflow[g * 2 + 1]};
#pragma unroll
    for (int i = 0; i < 11; ++i) {
      id_lds[r][i] = idv[i];
      A_lds[swz(r, i)] = f2bf(idv[i]);      // ff identity cols
    }
    for (int c = 231; c < 256; ++c) A_lds[swz(r, c)] = 0;  // K-pad
  }
  __syncthreads();

  // ---- Phase 0b: fourier via exact-arg revolutions + v_sin/v_cos.
  // sin(id*pi*2^k) = sin(2*pi * id*2^(k-1)); rev = id*2^(k-1) is EXACT (pow2),
  // fract(rev) is exact -> arg error only pi_f32-rounding class (~7e-4 max),
  // far under bf16 storage rounding.
  for (int e = tid; e < 704; e += 512) {
    int r = e & 63, i = e >> 6;
    float rev = id_lds[r][i] * 0.5f;
#pragma unroll
    for (int k = 0; k < 10; ++k) {
      float f = rev - floorf(rev);
      float s = __builtin_amdgcn_sinf(f);
      float c = __builtin_amdgcn_cosf(f);
      A_lds[swz(r, 11 + i * 10 + k)] = f2bf(s);
      A_lds[swz(r, 121 + i * 10 + k)] = f2bf(c);
      rev *= 2.0f;
    }
  }
  __syncthreads();

  // ---- Phase 1: h = relu(ff @ w_pos1 + b1)   (M=64,K=256pad,N=256) -> B
  {
    f32x4 acc[4][2] = {};
    gemm_mfma<2>(A_lds, WF, 16, wid * 2, lane, acc);
    epilogue<2, true>(acc, b1, wid * 32, B_lds, wid * 32, lane);
  }
  __syncthreads();

  // ---- Phase 2a: gather local_geo -> A (overwrites dead ff region)
  if (HWC) {
    const int r = tid >> 3;
    const int s = tid & 7;           // 32-channel slice
    const unsigned short* gh = wsh + WS_WEIGHTS_USHORTS;
    const unsigned short* g00 = gh + (size_t)qo_[0][r] * 256 + s * 32;
    const unsigned short* g01 = gh + (size_t)qo_[1][r] * 256 + s * 32;
    const unsigned short* g10 = gh + (size_t)qo_[2][r] * 256 + s * 32;
    const unsigned short* g11 = gh + (size_t)qo_[3][r] * 256 + s * 32;
    float w00 = qw[0][r], w01 = qw[1][r], w10 = qw[2][r], w11 = qw[3][r];
#pragma unroll
    for (int u = 0; u < 4; ++u) {    // 8 channels per iteration
      short8 a = *reinterpret_cast<const short8*>(g00 + u * 8);
      short8 b = *reinterpret_cast<const short8*>(g01 + u * 8);
      short8 c = *reinterpret_cast<const short8*>(g10 + u * 8);
      short8 d = *reinterpret_cast<const short8*>(g11 + u * 8);
      short8 res;
      __hip_bfloat162* rp = reinterpret_cast<__hip_bfloat162*>(&res);
#pragma unroll
      for (int p = 0; p < 4; ++p) {
        float v0 = w00 * bf2f((unsigned short)a[2 * p]) + w01 * bf2f((unsigned short)b[2 * p]) +
                   w10 * bf2f((unsigned short)c[2 * p]) + w11 * bf2f((unsigned short)d[2 * p]);
        float v1 = w00 * bf2f((unsigned short)a[2 * p + 1]) + w01 * bf2f((unsigned short)b[2 * p + 1]) +
                   w10 * bf2f((unsigned short)c[2 * p + 1]) + w11 * bf2f((unsigned short)d[2 * p + 1]);
        rp[p] = __float22bfloat162_rn(float2{v0, v1});
      }
      *reinterpret_cast<short8*>(&A_lds[swz(r, s * 32 + u * 8)]) = res;
    }
  } else {
    const int r = tid >> 3;
    const int c0 = (tid & 7) << 5;
    int o00 = qo_[0][r], o01 = qo_[1][r], o10 = qo_[2][r], o11 = qo_[3][r];
    float w00 = qw[0][r], w01 = qw[1][r], w10 = qw[2][r], w11 = qw[3][r];
    const float* gp = grid + (size_t)c0 * HW_GRID;
#pragma unroll 4
    for (int cc = 0; cc < 32; ++cc, gp += HW_GRID) {
      float v = w00 * gp[o00] + w01 * gp[o01] + w10 * gp[o10] + w11 * gp[o11];
      A_lds[swz(r, c0 + cc)] = f2bf(v);
    }
  }
  __syncthreads();

  // ---- Phase 3: h2 = relu([geo, pos_enc] @ w_pred1 + b3), K=768 split in 3,
  //      pos_enc computed in two 256-col halves into A (reg-resident acc3).
  f32x4 acc3[4][2] = {};
  gemm_mfma<2>(A_lds, WF3, 16, wid * 2, lane, acc3);              // += geo @ W3[0:256]
  __syncthreads();
  {
    f32x4 acc2[4][2] = {};
    gemm_mfma<2>(B_lds, WF2, 32, wid * 2, lane, acc2);            // pos1 = h @ W2[:,0:256]
    epilogue<2, false>(acc2, b2, wid * 32, A_lds, wid * 32, lane);
  }
  __syncthreads();
  gemm_mfma<2>(A_lds, WF3 + 8192, 16, wid * 2, lane, acc3);       // += pos1 @ W3[256:512]
  __syncthreads();
  {
    f32x4 acc2[4][2] = {};
    gemm_mfma<2>(B_lds, WF2, 32, 16 + wid * 2, lane, acc2);       // pos2 = h @ W2[:,256:512]
    epilogue<2, false>(acc2, b2 + 256, wid * 32, A_lds, wid * 32, lane);
  }
  __syncthreads();
  gemm_mfma<2>(A_lds, WF3 + 16384, 16, wid * 2, lane, acc3);      // += pos2 @ W3[512:768]
  epilogue<2, true>(acc3, b3, wid * 32, B_lds, wid * 32, lane);   // h2 -> B (h dead)
  __syncthreads();

  // ---- Phase 4: out = h2 @ w_pred2 + b4  (split-K x2, shuffle reduce)
  {
    const int r = tid >> 3, j = (tid >> 1) & 3, kq = tid & 1;
    float sum = 0.0f;
#pragma unroll
    for (int t = 0; t < 16; ++t) {
      int c0 = kq * 8 + t * 16;
      short8 v = *reinterpret_cast<const short8*>(&B_lds[swz(r, c0)]);
#pragma unroll
      for (int u = 0; u < 8; ++u)
        sum += bf2f((unsigned short)v[u]) * w4[(c0 + u) * 4 + j];
    }
    sum += __shfl_xor(sum, 1);
    if (kq == 0) {
      int g = row0 + r;
      if (g < N) out[g * 4 + j] = sum + b4[j];
    }
  }
}

extern "C" void kernel_launch(void* const* d_in, const int* in_sizes, int n_in,
                              void* d_out, int out_size, void* d_ws, size_t ws_size,
                              hipStream_t stream) {
  const float* grid  = (const float*)d_in[0];
  const float* sgrad = (const float*)d_in[1];
  const float* qpos  = (const float*)d_in[2];
  const float* quinf = (const float*)d_in[3];
  const float* qsdf  = (const float*)d_in[4];
  const float* qnrm  = (const float*)d_in[5];
  const float* qflow = (const float*)d_in[6];
  const float* w1 = (const float*)d_in[7];
  const float* b1 = (const float*)d_in[8];
  const float* w2 = (const float*)d_in[9];
  const float* b2 = (const float*)d_in[10];
  const float* w3 = (const float*)d_in[11];
  const float* b3 = (const float*)d_in[12];
  const float* w4 = (const float*)d_in[13];
  const float* b4 = (const float*)d_in[14];
  float* out = (float*)d_out;
  unsigned short* wsh = (unsigned short*)d_ws;

  const int N = in_sizes[2] / 2;  // 200000
  const bool hwc = ws_size >= (size_t)(WS_WEIGHTS_USHORTS + WS_GRID_USHORTS) * 2;

  prep_weights<<<768, 256, 0, stream>>>(w1, w2, w3, wsh);
  if (hwc) {
    prep_grid<<<HW_GRID / 32, 256, 0, stream>>>(grid, wsh + WS_WEIGHTS_USHORTS);
    fused_decoder<true><<<(N + 63) / 64, 512, 0, stream>>>(
        grid, sgrad, qpos, quinf, qsdf, qnrm, qflow,
        b1, b2, b3, w4, b4, wsh, out, N);
  } else {
    fused_decoder<false><<<(N + 63) / 64, 512, 0, stream>>>(
        grid, sgrad, qpos, quinf, qsdf, qnrm, qflow,
        b1, b2, b3, w4, b4, wsh, out, N);
  }
}

// Round 4
// 903.677 us; speedup vs baseline: 1.4559x; 1.4559x over previous
//
#include <hip/hip_runtime.h>
#include <hip/hip_bf16.h>

typedef __attribute__((ext_vector_type(8))) short short8;
typedef __attribute__((ext_vector_type(4))) float f32x4;

#define HW_GRID (256 * 512)
#define WS_WEIGHTS_USHORTS 393216        // 786 KB of bf16 weight fragments
#define WS_GRID_USHORTS (HW_GRID * 256)  // 67 MB bf16 HWC grid

__device__ __forceinline__ unsigned short f2bf(float f) {
  union { float f; unsigned int u; } v; v.f = f;
  unsigned int u = v.u;
  u += 0x7FFFu + ((u >> 16) & 1u);   // round-to-nearest-even
  return (unsigned short)(u >> 16);
}
__device__ __forceinline__ float bf2f(unsigned short b) {
  union { unsigned int u; float f; } v; v.u = ((unsigned int)b) << 16;
  return v.f;
}

// MFMA B-fragment layout for 16x16x32: B[k][j] lives at lane=((k%32)/8)*16 + j%16, elem=k%8
__device__ __forceinline__ int frag_off(int k, int j, int nf) {
  int kstep = k >> 5, ke = k & 31;
  int lane = ((ke >> 3) << 4) | (j & 15);
  int e = ke & 7;
  int nfrag = j >> 4;
  return (((kstep * nf + nfrag) << 6) + lane) * 8 + e;
}

__global__ void prep_weights(const float* __restrict__ w1, const float* __restrict__ w2,
                             const float* __restrict__ w3, unsigned short* __restrict__ ws) {
  int idx = blockIdx.x * 256 + threadIdx.x;
  if (idx < 65536) {               // w_pos1: K=256 (padded from 231) x N=256
    int k = idx >> 8, j = idx & 255;
    float v = (k < 231) ? w1[k * 256 + j] : 0.0f;
    ws[frag_off(k, j, 16)] = f2bf(v);
  }
  if (idx < 131072) {              // w_pos2: K=256 x N=512
    int k = idx >> 9, j = idx & 511;
    ws[65536 + frag_off(k, j, 32)] = f2bf(w2[k * 512 + j]);
  }
  if (idx < 196608) {              // w_pred1: K=768 x N=256
    int k = idx >> 8, j = idx & 255;
    ws[196608 + frag_off(k, j, 16)] = f2bf(w3[k * 256 + j]);
  }
}

// CHW fp32 -> HWC bf16 transpose. Block: 256 thr, 32 consecutive pixels x 256 ch.
__global__ __launch_bounds__(256) void prep_grid(const float* __restrict__ grid,
                                                 unsigned short* __restrict__ gh) {
  __shared__ unsigned short t_lds[32][264];   // +8 pad: spreads LDS banks on read
  const int pix0 = blockIdx.x * 32;
  const int xl = threadIdx.x & 31;            // pixel within block
  const int cg = threadIdx.x >> 5;            // 8 channel groups
#pragma unroll 8
  for (int cc = 0; cc < 32; ++cc) {
    int c = cg * 32 + cc;
    t_lds[xl][c] = f2bf(grid[(size_t)c * HW_GRID + pix0 + xl]);  // coalesced along x
  }
  __syncthreads();
  const int p = threadIdx.x >> 3;             // pixel
  const int s = threadIdx.x & 7;              // 32-ch slice
  unsigned short* dst = gh + ((size_t)(pix0 + p)) * 256 + s * 32;
  const unsigned short* src = &t_lds[p][s * 32];
#pragma unroll
  for (int u = 0; u < 4; ++u)
    *reinterpret_cast<short8*>(dst + u * 8) =
        *reinterpret_cast<const short8*>(src + u * 8);           // coalesced along c
}

// XOR-swizzled LDS index (ushort units). Kills 32-way bank conflict on
// stride-512B row-major ds_read_b128 (Guideline 4 / T2).
__device__ __forceinline__ int swz(int row, int col) {
  int byte = (col << 1) ^ ((row & 7) << 4);
  return row * 256 + (byte >> 1);
}

// A-tile (64 x 256, bf16, swizzled LDS) @ B (frag-order) -> acc[4][NW], K=256
template<int NW>
__device__ __forceinline__ void gemm_mfma(const unsigned short* __restrict__ At,
                                          const short8* __restrict__ Bf,
                                          int nftot, int nf0, int lane,
                                          f32x4 acc[4][NW]) {
  const int arow = lane & 15;
  const int acol = (lane >> 4) << 3;
  for (int ks = 0; ks < 8; ++ks) {
    short8 a[4];
#pragma unroll
    for (int m = 0; m < 4; ++m)
      a[m] = *reinterpret_cast<const short8*>(&At[swz(m * 16 + arow, ks * 32 + acol)]);
#pragma unroll
    for (int n = 0; n < NW; ++n) {
      short8 b = Bf[(ks * nftot + nf0 + n) * 64 + lane];
#pragma unroll
      for (int m = 0; m < 4; ++m)
        acc[m][n] = __builtin_amdgcn_mfma_f32_16x16x32_bf16(a[m], b, acc[m][n], 0, 0, 0);
    }
  }
}

// C layout: col = lane&15, row = (lane>>4)*4 + reg  [measured m89/m91]
template<int NW, bool RELU>
__device__ __forceinline__ void epilogue(f32x4 acc[4][NW], const float* __restrict__ bias,
                                         int bcol0, unsigned short* __restrict__ dst,
                                         int dcol0, int lane) {
  const int jlo = lane & 15;
  const int rhi = (lane >> 4) << 2;
#pragma unroll
  for (int n = 0; n < NW; ++n) {
    float bv = bias[bcol0 + n * 16 + jlo];
#pragma unroll
    for (int m = 0; m < 4; ++m) {
#pragma unroll
      for (int t = 0; t < 4; ++t) {
        float v = acc[m][n][t] + bv;
        if (RELU) v = fmaxf(v, 0.0f);
        dst[swz(m * 16 + rhi + t, dcol0 + n * 16 + jlo)] = f2bf(v);
      }
    }
  }
}

template<bool HWC>
__global__ __launch_bounds__(512, 2) void fused_decoder(
    const float* __restrict__ grid, const float* __restrict__ sgrad,
    const float* __restrict__ qpos, const float* __restrict__ quinf,
    const float* __restrict__ qsdf, const float* __restrict__ qnrm,
    const float* __restrict__ qflow,
    const float* __restrict__ b1, const float* __restrict__ b2,
    const float* __restrict__ b3, const float* __restrict__ w4,
    const float* __restrict__ b4,
    const unsigned short* __restrict__ wsh,
    float* __restrict__ out, int N) {
  // A: ff -> geo -> pos_enc half1 -> pos_enc half2.  B: h -> h2.
  __shared__ __align__(16) unsigned short A_lds[64 * 256];   // 32 KB
  __shared__ __align__(16) unsigned short B_lds[64 * 256];   // 32 KB
  __shared__ int qo_[4][64];
  __shared__ float qw[4][64];
  __shared__ float id_lds[64][12];

  const int tid = threadIdx.x;
  const int lane = tid & 63;
  const int wid = tid >> 6;
  const int row0 = blockIdx.x << 6;
  const short8* WF = (const short8*)wsh;            // w_pos1 frags
  const short8* WF2 = (const short8*)(wsh + 65536); // w_pos2
  const short8* WF3 = (const short8*)(wsh + 196608);// w_pred1 (24 ksteps x 16 nf)

  // ---- Phase 0a: per-row coords, sdf-grad gather, identity (threads 0..63)
  if (tid < 64) {
    const int r = tid;
    int g = row0 + r; if (g >= N) g = N - 1;
    float px = qpos[g * 2], py = qpos[g * 2 + 1];
    float xn = 2.0f * (px - (-2.0f)) / 6.0f - 1.0f;
    float yn = 2.0f * (py - (-1.5f)) / 3.0f - 1.0f;
    xn = fminf(fmaxf(xn, -1.0f), 1.0f);
    yn = fminf(fmaxf(yn, -1.0f), 1.0f);
    float ix = (xn + 1.0f) * 0.5f * 511.0f;
    float iy = (yn + 1.0f) * 0.5f * 255.0f;
    float x0f = floorf(ix), y0f = floorf(iy);
    float wx = ix - x0f, wy = iy - y0f;
    int x0 = (int)fminf(fmaxf(x0f, 0.0f), 511.0f);
    int x1 = (int)fminf(fmaxf(x0f + 1.0f, 0.0f), 511.0f);
    int y0 = (int)fminf(fmaxf(y0f, 0.0f), 255.0f);
    int y1 = (int)fminf(fmaxf(y0f + 1.0f, 0.0f), 255.0f);
    int o00 = y0 * 512 + x0, o01 = y0 * 512 + x1, o10 = y1 * 512 + x0, o11 = y1 * 512 + x1;
    qo_[0][r] = o00; qo_[1][r] = o01; qo_[2][r] = o10; qo_[3][r] = o11;
    float w00 = (1.0f - wx) * (1.0f - wy), w01 = wx * (1.0f - wy);
    float w10 = (1.0f - wx) * wy,          w11 = wx * wy;
    qw[0][r] = w00; qw[1][r] = w01; qw[2][r] = w10; qw[3][r] = w11;
    float sg0 = w00 * sgrad[o00] + w01 * sgrad[o01] + w10 * sgrad[o10] + w11 * sgrad[o11];
    const float* s1 = sgrad + HW_GRID;
    float sg1 = w00 * s1[o00] + w01 * s1[o01] + w10 * s1[o10] + w11 * s1[o11];
    float idv[11] = {px, py, quinf[g * 2], quinf[g * 2 + 1], qsdf[g], sg0, sg1,
                     qnrm[g * 2], qnrm[g * 2 + 1], qflow[g * 2], qflow[g * 2 + 1]};
#pragma unroll
    for (int i = 0; i < 11; ++i) {
      id_lds[r][i] = idv[i];
      A_lds[swz(r, i)] = f2bf(idv[i]);      // ff identity cols
    }
    for (int c = 231; c < 256; ++c) A_lds[swz(r, c)] = 0;  // K-pad
  }
  __syncthreads();

  // ---- Phase 0b: fourier via exact-arg revolutions + v_sin/v_cos.
  // sin(id*pi*2^k) = sin(2*pi * id*2^(k-1)); rev = id*2^(k-1) is EXACT (pow2),
  // fract(rev) is exact -> arg error only pi_f32-rounding class (~7e-4 max),
  // far under bf16 storage rounding.
  for (int e = tid; e < 704; e += 512) {
    int r = e & 63, i = e >> 6;
    float rev = id_lds[r][i] * 0.5f;
#pragma unroll
    for (int k = 0; k < 10; ++k) {
      float f = rev - floorf(rev);
      float s = __builtin_amdgcn_sinf(f);
      float c = __builtin_amdgcn_cosf(f);
      A_lds[swz(r, 11 + i * 10 + k)] = f2bf(s);
      A_lds[swz(r, 121 + i * 10 + k)] = f2bf(c);
      rev *= 2.0f;
    }
  }
  __syncthreads();

  // ---- Phase 1: h = relu(ff @ w_pos1 + b1)   (M=64,K=256pad,N=256) -> B
  {
    f32x4 acc[4][2] = {};
    gemm_mfma<2>(A_lds, WF, 16, wid * 2, lane, acc);
    epilogue<2, true>(acc, b1, wid * 32, B_lds, wid * 32, lane);
  }
  __syncthreads();

  // ---- Phase 2a: gather local_geo -> A (overwrites dead ff region)
  if (HWC) {
    const int r = tid >> 3;
    const int s = tid & 7;           // 32-channel slice
    const unsigned short* gh = wsh + WS_WEIGHTS_USHORTS;
    const unsigned short* g00 = gh + (size_t)qo_[0][r] * 256 + s * 32;
    const unsigned short* g01 = gh + (size_t)qo_[1][r] * 256 + s * 32;
    const unsigned short* g10 = gh + (size_t)qo_[2][r] * 256 + s * 32;
    const unsigned short* g11 = gh + (size_t)qo_[3][r] * 256 + s * 32;
    float w00 = qw[0][r], w01 = qw[1][r], w10 = qw[2][r], w11 = qw[3][r];
#pragma unroll
    for (int u = 0; u < 4; ++u) {    // 8 channels per iteration
      short8 a = *reinterpret_cast<const short8*>(g00 + u * 8);
      short8 b = *reinterpret_cast<const short8*>(g01 + u * 8);
      short8 c = *reinterpret_cast<const short8*>(g10 + u * 8);
      short8 d = *reinterpret_cast<const short8*>(g11 + u * 8);
      short8 res;
      __hip_bfloat162* rp = reinterpret_cast<__hip_bfloat162*>(&res);
#pragma unroll
      for (int p = 0; p < 4; ++p) {
        float v0 = w00 * bf2f((unsigned short)a[2 * p]) + w01 * bf2f((unsigned short)b[2 * p]) +
                   w10 * bf2f((unsigned short)c[2 * p]) + w11 * bf2f((unsigned short)d[2 * p]);
        float v1 = w00 * bf2f((unsigned short)a[2 * p + 1]) + w01 * bf2f((unsigned short)b[2 * p + 1]) +
                   w10 * bf2f((unsigned short)c[2 * p + 1]) + w11 * bf2f((unsigned short)d[2 * p + 1]);
        rp[p] = __float22bfloat162_rn(float2{v0, v1});
      }
      *reinterpret_cast<short8*>(&A_lds[swz(r, s * 32 + u * 8)]) = res;
    }
  } else {
    const int r = tid >> 3;
    const int c0 = (tid & 7) << 5;
    int o00 = qo_[0][r], o01 = qo_[1][r], o10 = qo_[2][r], o11 = qo_[3][r];
    float w00 = qw[0][r], w01 = qw[1][r], w10 = qw[2][r], w11 = qw[3][r];
    const float* gp = grid + (size_t)c0 * HW_GRID;
#pragma unroll 4
    for (int cc = 0; cc < 32; ++cc, gp += HW_GRID) {
      float v = w00 * gp[o00] + w01 * gp[o01] + w10 * gp[o10] + w11 * gp[o11];
      A_lds[swz(r, c0 + cc)] = f2bf(v);
    }
  }
  __syncthreads();

  // ---- Phase 3: h2 = relu([geo, pos_enc] @ w_pred1 + b3), K=768 split in 3,
  //      pos_enc computed in two 256-col halves into A (reg-resident acc3).
  f32x4 acc3[4][2] = {};
  gemm_mfma<2>(A_lds, WF3, 16, wid * 2, lane, acc3);              // += geo @ W3[0:256]
  __syncthreads();
  {
    f32x4 acc2[4][2] = {};
    gemm_mfma<2>(B_lds, WF2, 32, wid * 2, lane, acc2);            // pos1 = h @ W2[:,0:256]
    epilogue<2, false>(acc2, b2, wid * 32, A_lds, wid * 32, lane);
  }
  __syncthreads();
  gemm_mfma<2>(A_lds, WF3 + 8192, 16, wid * 2, lane, acc3);       // += pos1 @ W3[256:512]
  __syncthreads();
  {
    f32x4 acc2[4][2] = {};
    gemm_mfma<2>(B_lds, WF2, 32, 16 + wid * 2, lane, acc2);       // pos2 = h @ W2[:,256:512]
    epilogue<2, false>(acc2, b2 + 256, wid * 32, A_lds, wid * 32, lane);
  }
  __syncthreads();
  gemm_mfma<2>(A_lds, WF3 + 16384, 16, wid * 2, lane, acc3);      // += pos2 @ W3[512:768]
  epilogue<2, true>(acc3, b3, wid * 32, B_lds, wid * 32, lane);   // h2 -> B (h dead)
  __syncthreads();

  // ---- Phase 4: out = h2 @ w_pred2 + b4  (split-K x2, shuffle reduce)
  {
    const int r = tid >> 3, j = (tid >> 1) & 3, kq = tid & 1;
    float sum = 0.0f;
#pragma unroll
    for (int t = 0; t < 16; ++t) {
      int c0 = kq * 8 + t * 16;
      short8 v = *reinterpret_cast<const short8*>(&B_lds[swz(r, c0)]);
#pragma unroll
      for (int u = 0; u < 8; ++u)
        sum += bf2f((unsigned short)v[u]) * w4[(c0 + u) * 4 + j];
    }
    sum += __shfl_xor(sum, 1);
    if (kq == 0) {
      int g = row0 + r;
      if (g < N) out[g * 4 + j] = sum + b4[j];
    }
  }
}

extern "C" void kernel_launch(void* const* d_in, const int* in_sizes, int n_in,
                              void* d_out, int out_size, void* d_ws, size_t ws_size,
                              hipStream_t stream) {
  const float* grid  = (const float*)d_in[0];
  const float* sgrad = (const float*)d_in[1];
  const float* qpos  = (const float*)d_in[2];
  const float* quinf = (const float*)d_in[3];
  const float* qsdf  = (const float*)d_in[4];
  const float* qnrm  = (const float*)d_in[5];
  const float* qflow = (const float*)d_in[6];
  const float* w1 = (const float*)d_in[7];
  const float* b1 = (const float*)d_in[8];
  const float* w2 = (const float*)d_in[9];
  const float* b2 = (const float*)d_in[10];
  const float* w3 = (const float*)d_in[11];
  const float* b3 = (const float*)d_in[12];
  const float* w4 = (const float*)d_in[13];
  const float* b4 = (const float*)d_in[14];
  float* out = (float*)d_out;
  unsigned short* wsh = (unsigned short*)d_ws;

  const int N = in_sizes[2] / 2;  // 200000
  const bool hwc = ws_size >= (size_t)(WS_WEIGHTS_USHORTS + WS_GRID_USHORTS) * 2;

  prep_weights<<<768, 256, 0, stream>>>(w1, w2, w3, wsh);
  if (hwc) {
    prep_grid<<<HW_GRID / 32, 256, 0, stream>>>(grid, wsh + WS_WEIGHTS_USHORTS);
    fused_decoder<true><<<(N + 63) / 64, 512, 0, stream>>>(
        grid, sgrad, qpos, quinf, qsdf, qnrm, qflow,
        b1, b2, b3, w4, b4, wsh, out, N);
  } else {
    fused_decoder<false><<<(N + 63) / 64, 512, 0, stream>>>(
        grid, sgrad, qpos, quinf, qsdf, qnrm, qflow,
        b1, b2, b3, w4, b4, wsh, out, N);
  }
}

// Round 5
// 350.630 us; speedup vs baseline: 3.7523x; 2.5773x over previous
//
#include <hip/hip_runtime.h>
#include <hip/hip_bf16.h>

typedef __attribute__((ext_vector_type(8))) short short8;
typedef __attribute__((ext_vector_type(4))) float f32x4;

#define HW_GRID (256 * 512)
// workspace layout (ushort offsets)
#define OFF_W1F   0          // w_pos1 frags           (65536)
#define OFF_W23F  65536      // W23 = W2@W3b frags     (65536)
#define OFF_W3AF  131072     // w_pred1[0:256] frags   (65536)
#define OFF_B3P   196608     // b3' 256 floats         (512 ushorts)
#define OFF_TMPW  197120     // W23 fp32 tmp           (131072 ushorts)
#define OFF_GRID  335872     // HWC bf16 grid          (HW_GRID*256)
#define WS_TOTAL_USHORTS (OFF_GRID + (size_t)HW_GRID * 256)

__device__ __forceinline__ unsigned short f2bf(float f) {
  union { float f; unsigned int u; } v; v.f = f;
  unsigned int u = v.u;
  u += 0x7FFFu + ((u >> 16) & 1u);   // round-to-nearest-even
  return (unsigned short)(u >> 16);
}
__device__ __forceinline__ float bf2f(unsigned short b) {
  union { unsigned int u; float f; } v; v.u = ((unsigned int)b) << 16;
  return v.f;
}

// MFMA B-fragment layout for 16x16x32: B[k][j] lives at lane=((k%32)/8)*16 + j%16, elem=k%8
__device__ __forceinline__ int frag_off(int k, int j, int nf) {
  int kstep = k >> 5, ke = k & 31;
  int lane = ((ke >> 3) << 4) | (j & 15);
  int e = ke & 7;
  int nfrag = j >> 4;
  return (((kstep * nf + nfrag) << 6) + lane) * 8 + e;
}

// W23[k][j] = sum_i W2[k][i] * W3[256+i][j]  (fp32); also b3'[j] = b3[j] + sum_i b2[i]*W3[256+i][j]
__global__ __launch_bounds__(256) void prep_w23(const float* __restrict__ w2,
                                                const float* __restrict__ w3,
                                                const float* __restrict__ b2,
                                                const float* __restrict__ b3,
                                                float* __restrict__ tmp,
                                                float* __restrict__ b3p) {
  int idx = blockIdx.x * 256 + threadIdx.x;   // 65536 threads
  int k = idx >> 8, j = idx & 255;
  float s = 0.0f;
  for (int i = 0; i < 512; ++i)
    s += w2[k * 512 + i] * w3[(256 + i) * 256 + j];
  tmp[idx] = s;
  if (idx < 256) {
    float t = b3[idx];
    for (int i = 0; i < 512; ++i) t += b2[i] * w3[(256 + i) * 256 + idx];
    b3p[idx] = t;
  }
}

__global__ __launch_bounds__(256) void prep_weights(const float* __restrict__ w1,
                                                    const float* __restrict__ tmpw23,
                                                    const float* __restrict__ w3,
                                                    unsigned short* __restrict__ ws) {
  int idx = blockIdx.x * 256 + threadIdx.x;   // 65536 threads
  int k = idx >> 8, j = idx & 255;
  float v1 = (k < 231) ? w1[k * 256 + j] : 0.0f;     // K-pad 231->256
  ws[OFF_W1F + frag_off(k, j, 16)] = f2bf(v1);
  ws[OFF_W23F + frag_off(k, j, 16)] = f2bf(tmpw23[idx]);
  ws[OFF_W3AF + frag_off(k, j, 16)] = f2bf(w3[k * 256 + j]);  // geo rows 0..255
}

// CHW fp32 -> HWC bf16 transpose. Block: 256 thr, 32 consecutive pixels x 256 ch.
__global__ __launch_bounds__(256) void prep_grid(const float* __restrict__ grid,
                                                 unsigned short* __restrict__ gh) {
  __shared__ unsigned short t_lds[32][264];   // +8 pad: spreads LDS banks on read
  const int pix0 = blockIdx.x * 32;
  const int xl = threadIdx.x & 31;            // pixel within block
  const int cg = threadIdx.x >> 5;            // 8 channel groups
#pragma unroll 8
  for (int cc = 0; cc < 32; ++cc) {
    int c = cg * 32 + cc;
    t_lds[xl][c] = f2bf(grid[(size_t)c * HW_GRID + pix0 + xl]);  // coalesced along x
  }
  __syncthreads();
  const int p = threadIdx.x >> 3;             // pixel
  const int s = threadIdx.x & 7;              // 32-ch slice
  unsigned short* dst = gh + ((size_t)(pix0 + p)) * 256 + s * 32;
  const unsigned short* src = &t_lds[p][s * 32];
#pragma unroll
  for (int u = 0; u < 4; ++u)
    *reinterpret_cast<short8*>(dst + u * 8) =
        *reinterpret_cast<const short8*>(src + u * 8);           // coalesced along c
}

// XOR-swizzled LDS index (ushort units). Kills 32-way bank conflict on
// stride-512B row-major ds_read_b128 (Guideline 4 / T2).
__device__ __forceinline__ int swz(int row, int col) {
  int byte = (col << 1) ^ ((row & 7) << 4);
  return row * 256 + (byte >> 1);
}

// A-tile (64 x 256, bf16, swizzled LDS) @ B (frag-order) -> acc[4][NW], K=256
template<int NW>
__device__ __forceinline__ void gemm_mfma(const unsigned short* __restrict__ At,
                                          const short8* __restrict__ Bf,
                                          int nftot, int nf0, int lane,
                                          f32x4 acc[4][NW]) {
  const int arow = lane & 15;
  const int acol = (lane >> 4) << 3;
  for (int ks = 0; ks < 8; ++ks) {
    short8 a[4];
#pragma unroll
    for (int m = 0; m < 4; ++m)
      a[m] = *reinterpret_cast<const short8*>(&At[swz(m * 16 + arow, ks * 32 + acol)]);
#pragma unroll
    for (int n = 0; n < NW; ++n) {
      short8 b = Bf[(ks * nftot + nf0 + n) * 64 + lane];
#pragma unroll
      for (int m = 0; m < 4; ++m)
        acc[m][n] = __builtin_amdgcn_mfma_f32_16x16x32_bf16(a[m], b, acc[m][n], 0, 0, 0);
    }
  }
}

// C layout: col = lane&15, row = (lane>>4)*4 + reg  [measured m89/m91]
template<int NW, bool RELU>
__device__ __forceinline__ void epilogue(f32x4 acc[4][NW], const float* __restrict__ bias,
                                         int bcol0, unsigned short* __restrict__ dst,
                                         int dcol0, int lane) {
  const int jlo = lane & 15;
  const int rhi = (lane >> 4) << 2;
#pragma unroll
  for (int n = 0; n < NW; ++n) {
    float bv = bias[bcol0 + n * 16 + jlo];
#pragma unroll
    for (int m = 0; m < 4; ++m) {
#pragma unroll
      for (int t = 0; t < 4; ++t) {
        float v = acc[m][n][t] + bv;
        if (RELU) v = fmaxf(v, 0.0f);
        dst[swz(m * 16 + rhi + t, dcol0 + n * 16 + jlo)] = f2bf(v);
      }
    }
  }
}

template<bool HWC>
__global__ __launch_bounds__(512, 2) void fused_decoder(
    const float* __restrict__ grid, const float* __restrict__ sgrad,
    const float* __restrict__ qpos, const float* __restrict__ quinf,
    const float* __restrict__ qsdf, const float* __restrict__ qnrm,
    const float* __restrict__ qflow,
    const float* __restrict__ b1, const float* __restrict__ b4v,
    const float* __restrict__ w4,
    const unsigned short* __restrict__ wsh,
    float* __restrict__ out, int N) {
  // A: ff -> geo -> h2.  B: h.
  __shared__ __align__(16) unsigned short A_lds[64 * 256];   // 32 KB
  __shared__ __align__(16) unsigned short B_lds[64 * 256];   // 32 KB
  __shared__ int qo_[4][64];
  __shared__ float qw[4][64];
  __shared__ float id_lds[64][12];

  const int tid = threadIdx.x;
  const int lane = tid & 63;
  const int wid = tid >> 6;
  const int row0 = blockIdx.x << 6;
  const short8* WF1  = (const short8*)(wsh + OFF_W1F);
  const short8* WF23 = (const short8*)(wsh + OFF_W23F);
  const short8* WF3A = (const short8*)(wsh + OFF_W3AF);
  const float*  b3p  = (const float*)(wsh + OFF_B3P);

  // ---- Phase 0a: per-row coords, sdf-grad gather, identity (threads 0..63)
  if (tid < 64) {
    const int r = tid;
    int g = row0 + r; if (g >= N) g = N - 1;
    float px = qpos[g * 2], py = qpos[g * 2 + 1];
    float xn = 2.0f * (px - (-2.0f)) / 6.0f - 1.0f;
    float yn = 2.0f * (py - (-1.5f)) / 3.0f - 1.0f;
    xn = fminf(fmaxf(xn, -1.0f), 1.0f);
    yn = fminf(fmaxf(yn, -1.0f), 1.0f);
    float ix = (xn + 1.0f) * 0.5f * 511.0f;
    float iy = (yn + 1.0f) * 0.5f * 255.0f;
    float x0f = floorf(ix), y0f = floorf(iy);
    float wx = ix - x0f, wy = iy - y0f;
    int x0 = (int)fminf(fmaxf(x0f, 0.0f), 511.0f);
    int x1 = (int)fminf(fmaxf(x0f + 1.0f, 0.0f), 511.0f);
    int y0 = (int)fminf(fmaxf(y0f, 0.0f), 255.0f);
    int y1 = (int)fminf(fmaxf(y0f + 1.0f, 0.0f), 255.0f);
    int o00 = y0 * 512 + x0, o01 = y0 * 512 + x1, o10 = y1 * 512 + x0, o11 = y1 * 512 + x1;
    qo_[0][r] = o00; qo_[1][r] = o01; qo_[2][r] = o10; qo_[3][r] = o11;
    float w00 = (1.0f - wx) * (1.0f - wy), w01 = wx * (1.0f - wy);
    float w10 = (1.0f - wx) * wy,          w11 = wx * wy;
    qw[0][r] = w00; qw[1][r] = w01; qw[2][r] = w10; qw[3][r] = w11;
    float sg0 = w00 * sgrad[o00] + w01 * sgrad[o01] + w10 * sgrad[o10] + w11 * sgrad[o11];
    const float* s1 = sgrad + HW_GRID;
    float sg1 = w00 * s1[o00] + w01 * s1[o01] + w10 * s1[o10] + w11 * s1[o11];
    float idv[11] = {px, py, quinf[g * 2], quinf[g * 2 + 1], qsdf[g], sg0, sg1,
                     qnrm[g * 2], qnrm[g * 2 + 1], qflow[g * 2], qflow[g * 2 + 1]};
#pragma unroll
    for (int i = 0; i < 11; ++i) {
      id_lds[r][i] = idv[i];
      A_lds[swz(r, i)] = f2bf(idv[i]);      // ff identity cols
    }
    for (int c = 231; c < 256; ++c) A_lds[swz(r, c)] = 0;  // K-pad
  }
  __syncthreads();

  // ---- Phase 0b: fourier via exact-arg revolutions + v_sin/v_cos.
  // sin(id*pi*2^k) = sin(2*pi * id*2^(k-1)); rev = id*2^(k-1) is EXACT (pow2),
  // fract(rev) is exact -> arg error only pi_f32-rounding class (~7e-4 max).
  for (int e = tid; e < 704; e += 512) {
    int r = e & 63, i = e >> 6;
    float rev = id_lds[r][i] * 0.5f;
#pragma unroll
    for (int k = 0; k < 10; ++k) {
      float f = rev - floorf(rev);
      float s = __builtin_amdgcn_sinf(f);
      float c = __builtin_amdgcn_cosf(f);
      A_lds[swz(r, 11 + i * 10 + k)] = f2bf(s);
      A_lds[swz(r, 121 + i * 10 + k)] = f2bf(c);
      rev *= 2.0f;
    }
  }
  __syncthreads();

  // ---- Phase 1: h = relu(ff @ w_pos1 + b1)   (M=64,K=256pad,N=256) -> B
  {
    f32x4 acc[4][2] = {};
    gemm_mfma<2>(A_lds, WF1, 16, wid * 2, lane, acc);
    epilogue<2, true>(acc, b1, wid * 32, B_lds, wid * 32, lane);
  }
  __syncthreads();   // all waves done reading A (ff) and writing B (h)

  // ---- Phase 2: gather local_geo -> A (ff dead)
  if (HWC) {
    const int r = tid >> 3;
    const int s = tid & 7;           // 32-channel slice
    const unsigned short* gh = wsh + OFF_GRID;
    const unsigned short* g00 = gh + (size_t)qo_[0][r] * 256 + s * 32;
    const unsigned short* g01 = gh + (size_t)qo_[1][r] * 256 + s * 32;
    const unsigned short* g10 = gh + (size_t)qo_[2][r] * 256 + s * 32;
    const unsigned short* g11 = gh + (size_t)qo_[3][r] * 256 + s * 32;
    float w00 = qw[0][r], w01 = qw[1][r], w10 = qw[2][r], w11 = qw[3][r];
#pragma unroll
    for (int u = 0; u < 4; ++u) {    // 8 channels per iteration
      short8 a = *reinterpret_cast<const short8*>(g00 + u * 8);
      short8 b = *reinterpret_cast<const short8*>(g01 + u * 8);
      short8 c = *reinterpret_cast<const short8*>(g10 + u * 8);
      short8 d = *reinterpret_cast<const short8*>(g11 + u * 8);
      short8 res;
      __hip_bfloat162* rp = reinterpret_cast<__hip_bfloat162*>(&res);
#pragma unroll
      for (int p = 0; p < 4; ++p) {
        float v0 = w00 * bf2f((unsigned short)a[2 * p]) + w01 * bf2f((unsigned short)b[2 * p]) +
                   w10 * bf2f((unsigned short)c[2 * p]) + w11 * bf2f((unsigned short)d[2 * p]);
        float v1 = w00 * bf2f((unsigned short)a[2 * p + 1]) + w01 * bf2f((unsigned short)b[2 * p + 1]) +
                   w10 * bf2f((unsigned short)c[2 * p + 1]) + w11 * bf2f((unsigned short)d[2 * p + 1]);
        rp[p] = __float22bfloat162_rn(float2{v0, v1});
      }
      *reinterpret_cast<short8*>(&A_lds[swz(r, s * 32 + u * 8)]) = res;
    }
  } else {
    const int r = tid >> 3;
    const int c0 = (tid & 7) << 5;
    int o00 = qo_[0][r], o01 = qo_[1][r], o10 = qo_[2][r], o11 = qo_[3][r];
    float w00 = qw[0][r], w01 = qw[1][r], w10 = qw[2][r], w11 = qw[3][r];
    const float* gp = grid + (size_t)c0 * HW_GRID;
#pragma unroll 4
    for (int cc = 0; cc < 32; ++cc, gp += HW_GRID) {
      float v = w00 * gp[o00] + w01 * gp[o01] + w10 * gp[o10] + w11 * gp[o11];
      A_lds[swz(r, c0 + cc)] = f2bf(v);
    }
  }
  __syncthreads();

  // ---- Phase 3: h2 = relu(geo@W3a + h@W23 + b3')  -- single acc, no interleave
  {
    f32x4 acc3[4][2] = {};
    gemm_mfma<2>(A_lds, WF3A, 16, wid * 2, lane, acc3);   // geo part
    gemm_mfma<2>(B_lds, WF23, 16, wid * 2, lane, acc3);   // h @ (W2@W3b)
    __syncthreads();                                      // drain all reads of A,B
    epilogue<2, true>(acc3, b3p, wid * 32, A_lds, wid * 32, lane);  // h2 -> A
  }
  __syncthreads();

  // ---- Phase 4: out = h2 @ w_pred2 + b4  (split-K x2, shuffle reduce)
  {
    const int r = tid >> 3, j = (tid >> 1) & 3, kq = tid & 1;
    float sum = 0.0f;
#pragma unroll
    for (int t = 0; t < 16; ++t) {
      int c0 = kq * 8 + t * 16;
      short8 v = *reinterpret_cast<const short8*>(&A_lds[swz(r, c0)]);
#pragma unroll
      for (int u = 0; u < 8; ++u)
        sum += bf2f((unsigned short)v[u]) * w4[(c0 + u) * 4 + j];
    }
    sum += __shfl_xor(sum, 1);
    if (kq == 0) {
      int g = row0 + r;
      if (g < N) out[g * 4 + j] = sum + b4v[j];
    }
  }
}

extern "C" void kernel_launch(void* const* d_in, const int* in_sizes, int n_in,
                              void* d_out, int out_size, void* d_ws, size_t ws_size,
                              hipStream_t stream) {
  const float* grid  = (const float*)d_in[0];
  const float* sgrad = (const float*)d_in[1];
  const float* qpos  = (const float*)d_in[2];
  const float* quinf = (const float*)d_in[3];
  const float* qsdf  = (const float*)d_in[4];
  const float* qnrm  = (const float*)d_in[5];
  const float* qflow = (const float*)d_in[6];
  const float* w1 = (const float*)d_in[7];
  const float* b1 = (const float*)d_in[8];
  const float* w2 = (const float*)d_in[9];
  const float* b2 = (const float*)d_in[10];
  const float* w3 = (const float*)d_in[11];
  const float* b3 = (const float*)d_in[12];
  const float* w4 = (const float*)d_in[13];
  const float* b4 = (const float*)d_in[14];
  float* out = (float*)d_out;
  unsigned short* wsh = (unsigned short*)d_ws;

  const int N = in_sizes[2] / 2;  // 200000
  const bool hwc = ws_size >= WS_TOTAL_USHORTS * 2;

  prep_w23<<<256, 256, 0, stream>>>(w2, w3, b2, b3,
                                    (float*)(wsh + OFF_TMPW), (float*)(wsh + OFF_B3P));
  prep_weights<<<256, 256, 0, stream>>>(w1, (const float*)(wsh + OFF_TMPW), w3, wsh);
  if (hwc) {
    prep_grid<<<HW_GRID / 32, 256, 0, stream>>>(grid, wsh + OFF_GRID);
    fused_decoder<true><<<(N + 63) / 64, 512, 0, stream>>>(
        grid, sgrad, qpos, quinf, qsdf, qnrm, qflow,
        b1, b4, w4, wsh, out, N);
  } else {
    fused_decoder<false><<<(N + 63) / 64, 512, 0, stream>>>(
        grid, sgrad, qpos, quinf, qsdf, qnrm, qflow,
        b1, b4, w4, wsh, out, N);
  }
}

// Round 6
// 305.711 us; speedup vs baseline: 4.3036x; 1.1469x over previous
//
#include <hip/hip_runtime.h>
#include <hip/hip_bf16.h>

typedef __attribute__((ext_vector_type(8))) short short8;
typedef __attribute__((ext_vector_type(4))) float f32x4;

#define HW_GRID (256 * 512)
// workspace layout (ushort offsets)
#define OFF_W1F   0          // w_pos1 frags           (65536)
#define OFF_W23F  65536      // W23 = W2@W3b frags     (65536)
#define OFF_W3AF  131072     // w_pred1[0:256] frags   (65536)
#define OFF_B3P   196608     // b3' 256 floats         (512 ushorts)
#define OFF_TMPW  197120     // W23 fp32 tmp           (131072 ushorts)
#define OFF_GRID  335872     // HWC bf16 grid          (HW_GRID*256)
#define WS_TOTAL_USHORTS (OFF_GRID + (size_t)HW_GRID * 256)

#define ROWS 32              // rows per block (32-row tiles -> ~35KB LDS -> 4 blocks/CU)

__device__ __forceinline__ unsigned short f2bf(float f) {
  union { float f; unsigned int u; } v; v.f = f;
  unsigned int u = v.u;
  u += 0x7FFFu + ((u >> 16) & 1u);   // round-to-nearest-even
  return (unsigned short)(u >> 16);
}
__device__ __forceinline__ float bf2f(unsigned short b) {
  union { unsigned int u; float f; } v; v.u = ((unsigned int)b) << 16;
  return v.f;
}

// MFMA B-fragment layout for 16x16x32: B[k][j] lives at lane=((k%32)/8)*16 + j%16, elem=k%8
__device__ __forceinline__ int frag_off(int k, int j, int nf) {
  int kstep = k >> 5, ke = k & 31;
  int lane = ((ke >> 3) << 4) | (j & 15);
  int e = ke & 7;
  int nfrag = j >> 4;
  return (((kstep * nf + nfrag) << 6) + lane) * 8 + e;
}

// W23[k][j] = sum_i W2[k][i] * W3[256+i][j]  (fp32); also b3'[j] = b3[j] + sum_i b2[i]*W3[256+i][j]
__global__ __launch_bounds__(256) void prep_w23(const float* __restrict__ w2,
                                                const float* __restrict__ w3,
                                                const float* __restrict__ b2,
                                                const float* __restrict__ b3,
                                                float* __restrict__ tmp,
                                                float* __restrict__ b3p) {
  int idx = blockIdx.x * 256 + threadIdx.x;   // 65536 threads
  int k = idx >> 8, j = idx & 255;
  float s = 0.0f;
  for (int i = 0; i < 512; ++i)
    s += w2[k * 512 + i] * w3[(256 + i) * 256 + j];
  tmp[idx] = s;
  if (idx < 256) {
    float t = b3[idx];
    for (int i = 0; i < 512; ++i) t += b2[i] * w3[(256 + i) * 256 + idx];
    b3p[idx] = t;
  }
}

__global__ __launch_bounds__(256) void prep_weights(const float* __restrict__ w1,
                                                    const float* __restrict__ tmpw23,
                                                    const float* __restrict__ w3,
                                                    unsigned short* __restrict__ ws) {
  int idx = blockIdx.x * 256 + threadIdx.x;   // 65536 threads
  int k = idx >> 8, j = idx & 255;
  float v1 = (k < 231) ? w1[k * 256 + j] : 0.0f;     // K-pad 231->256
  ws[OFF_W1F + frag_off(k, j, 16)] = f2bf(v1);
  ws[OFF_W23F + frag_off(k, j, 16)] = f2bf(tmpw23[idx]);
  ws[OFF_W3AF + frag_off(k, j, 16)] = f2bf(w3[k * 256 + j]);  // geo rows 0..255
}

// CHW fp32 -> HWC bf16 transpose. Block: 256 thr, 32 consecutive pixels x 256 ch.
__global__ __launch_bounds__(256) void prep_grid(const float* __restrict__ grid,
                                                 unsigned short* __restrict__ gh) {
  __shared__ unsigned short t_lds[32][264];   // +8 pad: spreads LDS banks on read
  const int pix0 = blockIdx.x * 32;
  const int xl = threadIdx.x & 31;            // pixel within block
  const int cg = threadIdx.x >> 5;            // 8 channel groups
#pragma unroll 8
  for (int cc = 0; cc < 32; ++cc) {
    int c = cg * 32 + cc;
    t_lds[xl][c] = f2bf(grid[(size_t)c * HW_GRID + pix0 + xl]);  // coalesced along x
  }
  __syncthreads();
  const int p = threadIdx.x >> 3;             // pixel
  const int s = threadIdx.x & 7;              // 32-ch slice
  unsigned short* dst = gh + ((size_t)(pix0 + p)) * 256 + s * 32;
  const unsigned short* src = &t_lds[p][s * 32];
#pragma unroll
  for (int u = 0; u < 4; ++u)
    *reinterpret_cast<short8*>(dst + u * 8) =
        *reinterpret_cast<const short8*>(src + u * 8);           // coalesced along c
}

// XOR-swizzled LDS index (ushort units). Kills 32-way bank conflict on
// stride-512B row-major ds_read_b128 (Guideline 4 / T2).
__device__ __forceinline__ int swz(int row, int col) {
  int byte = (col << 1) ^ ((row & 7) << 4);
  return row * 256 + (byte >> 1);
}

// A-tile (ROWS x 256, bf16, swizzled LDS) @ B (frag-order) -> acc[2][NW], K=256
template<int NW>
__device__ __forceinline__ void gemm_mfma(const unsigned short* __restrict__ At,
                                          const short8* __restrict__ Bf,
                                          int nftot, int nf0, int lane,
                                          f32x4 acc[2][NW]) {
  const int arow = lane & 15;
  const int acol = (lane >> 4) << 3;
  for (int ks = 0; ks < 8; ++ks) {
    short8 a[2];
#pragma unroll
    for (int m = 0; m < 2; ++m)
      a[m] = *reinterpret_cast<const short8*>(&At[swz(m * 16 + arow, ks * 32 + acol)]);
#pragma unroll
    for (int n = 0; n < NW; ++n) {
      short8 b = Bf[(ks * nftot + nf0 + n) * 64 + lane];
#pragma unroll
      for (int m = 0; m < 2; ++m)
        acc[m][n] = __builtin_amdgcn_mfma_f32_16x16x32_bf16(a[m], b, acc[m][n], 0, 0, 0);
    }
  }
}

// C layout: col = lane&15, row = (lane>>4)*4 + reg  [measured m89/m91]
template<int NW, bool RELU>
__device__ __forceinline__ void epilogue(f32x4 acc[2][NW], const float* __restrict__ bias,
                                         int bcol0, unsigned short* __restrict__ dst,
                                         int dcol0, int lane) {
  const int jlo = lane & 15;
  const int rhi = (lane >> 4) << 2;
#pragma unroll
  for (int n = 0; n < NW; ++n) {
    float bv = bias[bcol0 + n * 16 + jlo];
#pragma unroll
    for (int m = 0; m < 2; ++m) {
#pragma unroll
      for (int t = 0; t < 4; ++t) {
        float v = acc[m][n][t] + bv;
        if (RELU) v = fmaxf(v, 0.0f);
        dst[swz(m * 16 + rhi + t, dcol0 + n * 16 + jlo)] = f2bf(v);
      }
    }
  }
}

template<bool HWC>
__global__ __launch_bounds__(256, 4) void fused_decoder(
    const float* __restrict__ grid, const float* __restrict__ sgrad,
    const float* __restrict__ qpos, const float* __restrict__ quinf,
    const float* __restrict__ qsdf, const float* __restrict__ qnrm,
    const float* __restrict__ qflow,
    const float* __restrict__ b1, const float* __restrict__ b4v,
    const float* __restrict__ w4,
    const unsigned short* __restrict__ wsh,
    float* __restrict__ out, int N) {
  // A: ff -> geo -> h2.  B: h.
  __shared__ __align__(16) unsigned short A_lds[ROWS * 256];   // 16 KB
  __shared__ __align__(16) unsigned short B_lds[ROWS * 256];   // 16 KB
  __shared__ int qo_[4][ROWS];
  __shared__ float qw[4][ROWS];
  __shared__ float id_lds[ROWS][12];

  const int tid = threadIdx.x;
  const int lane = tid & 63;
  const int wid = tid >> 6;           // 4 waves
  const int row0 = blockIdx.x * ROWS;
  const short8* WF1  = (const short8*)(wsh + OFF_W1F);
  const short8* WF23 = (const short8*)(wsh + OFF_W23F);
  const short8* WF3A = (const short8*)(wsh + OFF_W3AF);
  const float*  b3p  = (const float*)(wsh + OFF_B3P);

  // ---- Phase 0a: per-row coords, sdf-grad gather, identity (threads 0..ROWS-1)
  if (tid < ROWS) {
    const int r = tid;
    int g = row0 + r; if (g >= N) g = N - 1;
    float px = qpos[g * 2], py = qpos[g * 2 + 1];
    float xn = 2.0f * (px - (-2.0f)) / 6.0f - 1.0f;
    float yn = 2.0f * (py - (-1.5f)) / 3.0f - 1.0f;
    xn = fminf(fmaxf(xn, -1.0f), 1.0f);
    yn = fminf(fmaxf(yn, -1.0f), 1.0f);
    float ix = (xn + 1.0f) * 0.5f * 511.0f;
    float iy = (yn + 1.0f) * 0.5f * 255.0f;
    float x0f = floorf(ix), y0f = floorf(iy);
    float wx = ix - x0f, wy = iy - y0f;
    int x0 = (int)fminf(fmaxf(x0f, 0.0f), 511.0f);
    int x1 = (int)fminf(fmaxf(x0f + 1.0f, 0.0f), 511.0f);
    int y0 = (int)fminf(fmaxf(y0f, 0.0f), 255.0f);
    int y1 = (int)fminf(fmaxf(y0f + 1.0f, 0.0f), 255.0f);
    int o00 = y0 * 512 + x0, o01 = y0 * 512 + x1, o10 = y1 * 512 + x0, o11 = y1 * 512 + x1;
    qo_[0][r] = o00; qo_[1][r] = o01; qo_[2][r] = o10; qo_[3][r] = o11;
    float w00 = (1.0f - wx) * (1.0f - wy), w01 = wx * (1.0f - wy);
    float w10 = (1.0f - wx) * wy,          w11 = wx * wy;
    qw[0][r] = w00; qw[1][r] = w01; qw[2][r] = w10; qw[3][r] = w11;
    float sg0 = w00 * sgrad[o00] + w01 * sgrad[o01] + w10 * sgrad[o10] + w11 * sgrad[o11];
    const float* s1 = sgrad + HW_GRID;
    float sg1 = w00 * s1[o00] + w01 * s1[o01] + w10 * s1[o10] + w11 * s1[o11];
    float idv[11] = {px, py, quinf[g * 2], quinf[g * 2 + 1], qsdf[g], sg0, sg1,
                     qnrm[g * 2], qnrm[g * 2 + 1], qflow[g * 2], qflow[g * 2 + 1]};
#pragma unroll
    for (int i = 0; i < 11; ++i) {
      id_lds[r][i] = idv[i];
      A_lds[swz(r, i)] = f2bf(idv[i]);      // ff identity cols
    }
    for (int c = 231; c < 256; ++c) A_lds[swz(r, c)] = 0;  // K-pad
  }
  __syncthreads();

  // ---- Phase 0b: fourier via exact-arg revolutions + v_sin/v_cos.
  // sin(id*pi*2^k) = sin(2*pi * id*2^(k-1)); rev = id*2^(k-1) is EXACT (pow2),
  // fract(rev) is exact -> arg error only pi_f32-rounding class (~7e-4 max).
  for (int e = tid; e < ROWS * 11; e += 256) {
    int r = e & (ROWS - 1), i = e / ROWS;
    float rev = id_lds[r][i] * 0.5f;
#pragma unroll
    for (int k = 0; k < 10; ++k) {
      float f = rev - floorf(rev);
      float s = __builtin_amdgcn_sinf(f);
      float c = __builtin_amdgcn_cosf(f);
      A_lds[swz(r, 11 + i * 10 + k)] = f2bf(s);
      A_lds[swz(r, 121 + i * 10 + k)] = f2bf(c);
      rev *= 2.0f;
    }
  }
  __syncthreads();

  // ---- Phase 1: h = relu(ff @ w_pos1 + b1)   (M=ROWS,K=256pad,N=256) -> B
  {
    f32x4 acc[2][4] = {};
    gemm_mfma<4>(A_lds, WF1, 16, wid * 4, lane, acc);
    epilogue<4, true>(acc, b1, wid * 64, B_lds, wid * 64, lane);
  }
  __syncthreads();   // all waves done reading A (ff) and writing B (h)

  // ---- Phase 2: gather local_geo -> A (ff dead)
  if (HWC) {
    const int r = tid >> 3;          // 32 rows
    const int s = tid & 7;           // 32-channel slice
    const unsigned short* gh = wsh + OFF_GRID;
    const unsigned short* g00 = gh + (size_t)qo_[0][r] * 256 + s * 32;
    const unsigned short* g01 = gh + (size_t)qo_[1][r] * 256 + s * 32;
    const unsigned short* g10 = gh + (size_t)qo_[2][r] * 256 + s * 32;
    const unsigned short* g11 = gh + (size_t)qo_[3][r] * 256 + s * 32;
    float w00 = qw[0][r], w01 = qw[1][r], w10 = qw[2][r], w11 = qw[3][r];
#pragma unroll
    for (int u = 0; u < 4; ++u) {    // 8 channels per iteration
      short8 a = *reinterpret_cast<const short8*>(g00 + u * 8);
      short8 b = *reinterpret_cast<const short8*>(g01 + u * 8);
      short8 c = *reinterpret_cast<const short8*>(g10 + u * 8);
      short8 d = *reinterpret_cast<const short8*>(g11 + u * 8);
      short8 res;
      __hip_bfloat162* rp = reinterpret_cast<__hip_bfloat162*>(&res);
#pragma unroll
      for (int p = 0; p < 4; ++p) {
        float v0 = w00 * bf2f((unsigned short)a[2 * p]) + w01 * bf2f((unsigned short)b[2 * p]) +
                   w10 * bf2f((unsigned short)c[2 * p]) + w11 * bf2f((unsigned short)d[2 * p]);
        float v1 = w00 * bf2f((unsigned short)a[2 * p + 1]) + w01 * bf2f((unsigned short)b[2 * p + 1]) +
                   w10 * bf2f((unsigned short)c[2 * p + 1]) + w11 * bf2f((unsigned short)d[2 * p + 1]);
        rp[p] = __float22bfloat162_rn(float2{v0, v1});
      }
      *reinterpret_cast<short8*>(&A_lds[swz(r, s * 32 + u * 8)]) = res;
    }
  } else {
    const int r = tid >> 3;
    const int c0 = (tid & 7) << 5;
    int o00 = qo_[0][r], o01 = qo_[1][r], o10 = qo_[2][r], o11 = qo_[3][r];
    float w00 = qw[0][r], w01 = qw[1][r], w10 = qw[2][r], w11 = qw[3][r];
    const float* gp = grid + (size_t)c0 * HW_GRID;
#pragma unroll 4
    for (int cc = 0; cc < 32; ++cc, gp += HW_GRID) {
      float v = w00 * gp[o00] + w01 * gp[o01] + w10 * gp[o10] + w11 * gp[o11];
      A_lds[swz(r, c0 + cc)] = f2bf(v);
    }
  }
  __syncthreads();

  // ---- Phase 3: h2 = relu(geo@W3a + h@W23 + b3')  -- single acc, no interleave
  {
    f32x4 acc3[2][4] = {};
    gemm_mfma<4>(A_lds, WF3A, 16, wid * 4, lane, acc3);   // geo part
    gemm_mfma<4>(B_lds, WF23, 16, wid * 4, lane, acc3);   // h @ (W2@W3b)
    __syncthreads();                                      // drain all reads of A,B
    epilogue<4, true>(acc3, b3p, wid * 64, A_lds, wid * 64, lane);  // h2 -> A
  }
  __syncthreads();

  // ---- Phase 4: out = h2 @ w_pred2 + b4  (split-K x2, shuffle reduce)
  {
    const int r = tid >> 3, j = (tid >> 1) & 3, kq = tid & 1;
    float sum = 0.0f;
#pragma unroll
    for (int t = 0; t < 16; ++t) {
      int c0 = kq * 8 + t * 16;
      short8 v = *reinterpret_cast<const short8*>(&A_lds[swz(r, c0)]);
#pragma unroll
      for (int u = 0; u < 8; ++u)
        sum += bf2f((unsigned short)v[u]) * w4[(c0 + u) * 4 + j];
    }
    sum += __shfl_xor(sum, 1);
    if (kq == 0) {
      int g = row0 + r;
      if (g < N) out[g * 4 + j] = sum + b4v[j];
    }
  }
}

extern "C" void kernel_launch(void* const* d_in, const int* in_sizes, int n_in,
                              void* d_out, int out_size, void* d_ws, size_t ws_size,
                              hipStream_t stream) {
  const float* grid  = (const float*)d_in[0];
  const float* sgrad = (const float*)d_in[1];
  const float* qpos  = (const float*)d_in[2];
  const float* quinf = (const float*)d_in[3];
  const float* qsdf  = (const float*)d_in[4];
  const float* qnrm  = (const float*)d_in[5];
  const float* qflow = (const float*)d_in[6];
  const float* w1 = (const float*)d_in[7];
  const float* b1 = (const float*)d_in[8];
  const float* w2 = (const float*)d_in[9];
  const float* b2 = (const float*)d_in[10];
  const float* w3 = (const float*)d_in[11];
  const float* b3 = (const float*)d_in[12];
  const float* w4 = (const float*)d_in[13];
  const float* b4 = (const float*)d_in[14];
  float* out = (float*)d_out;
  unsigned short* wsh = (unsigned short*)d_ws;

  const int N = in_sizes[2] / 2;  // 200000
  const bool hwc = ws_size >= WS_TOTAL_USHORTS * 2;

  prep_w23<<<256, 256, 0, stream>>>(w2, w3, b2, b3,
                                    (float*)(wsh + OFF_TMPW), (float*)(wsh + OFF_B3P));
  prep_weights<<<256, 256, 0, stream>>>(w1, (const float*)(wsh + OFF_TMPW), w3, wsh);
  if (hwc) {
    prep_grid<<<HW_GRID / 32, 256, 0, stream>>>(grid, wsh + OFF_GRID);
    fused_decoder<true><<<(N + ROWS - 1) / ROWS, 256, 0, stream>>>(
        grid, sgrad, qpos, quinf, qsdf, qnrm, qflow,
        b1, b4, w4, wsh, out, N);
  } else {
    fused_decoder<false><<<(N + ROWS - 1) / ROWS, 256, 0, stream>>>(
        grid, sgrad, qpos, quinf, qsdf, qnrm, qflow,
        b1, b4, w4, wsh, out, N);
  }
}